// Round 7
// baseline (288.780 us; speedup 1.0000x reference)
//
#include <hip/hip_runtime.h>

typedef unsigned short ushort_t;
typedef unsigned int uint_t;
typedef __attribute__((ext_vector_type(8))) short short8;   // 8 x bf16 (4 VGPRs)
typedef __attribute__((ext_vector_type(4))) float f32x4;
typedef __attribute__((ext_vector_type(2))) float f32x2;

#define B_   128
#define S_   1024
#define H_   256
#define T_   10
#define NEG_INF_ -1e8f

static __device__ __forceinline__ ushort_t f2bf(float x) {
    unsigned int u = __float_as_uint(x);
    unsigned int r = u + 0x7FFFu + ((u >> 16) & 1u);   // RNE
    return (ushort_t)(r >> 16);
}
static __device__ __forceinline__ float bf2f(ushort_t u) {
    return __uint_as_float(((unsigned int)u) << 16);
}
static __device__ __forceinline__ float sigf(float x) {
    return 1.0f / (1.0f + __expf(-x));
}
static __device__ __forceinline__ float tanh_acc(float x) {
    return 2.0f / (1.0f + __expf(-2.0f * x)) - 1.0f;
}
static __device__ __forceinline__ f32x2 sp2(float v) { return (f32x2){v, v}; }
// packed clamped odd-poly tanh (v_pk_* dual-issue fp32), |err|<~0.025
static __device__ __forceinline__ f32x2 tanh2(f32x2 x) {
    f32x2 u = x * x;
    f32x2 p = u * sp2(0.019063f) + sp2(-0.18852f);
    p = p * u + sp2(0.93106f);
    f32x2 r = x * p;
    r = __builtin_elementwise_max(r, sp2(-1.0f));
    r = __builtin_elementwise_min(r, sp2(1.0f));
    return r;
}
static __device__ __forceinline__ short8 pack_bf8(float4 a, float4 b) {
    short8 r;
    r[0] = (short)f2bf(a.x); r[1] = (short)f2bf(a.y);
    r[2] = (short)f2bf(a.z); r[3] = (short)f2bf(a.w);
    r[4] = (short)f2bf(b.x); r[5] = (short)f2bf(b.y);
    r[6] = (short)f2bf(b.z); r[7] = (short)f2bf(b.w);
    return r;
}

// ---------------------------------------------------------------------------
// prep_conv: W_hh/Wq/Wd -> bf16 row-major, mask output. grid = 1792*256.
// ---------------------------------------------------------------------------
__global__ void prep_conv(const float* __restrict__ W_hh, const float* __restrict__ Wq,
                          const float* __restrict__ Wd, const int* __restrict__ slen,
                          ushort_t* __restrict__ Whh_bf, ushort_t* __restrict__ Wq_bf,
                          ushort_t* __restrict__ Wd_bf, float* __restrict__ out_mask) {
    int i = blockIdx.x * 256 + threadIdx.x;
    if (i < 196608) { Whh_bf[i] = f2bf(W_hh[i]); return; }
    i -= 196608;
    if (i < 65536) { Wq_bf[i] = f2bf(Wq[i]); return; }
    i -= 65536;
    if (i < 65536) { Wd_bf[i] = f2bf(Wd[i]); return; }
    i -= 65536;
    int b = i >> 10, s = i & 1023;
    out_mask[i] = (s >= slen[b]) ? 1.0f : 0.0f;
}

// ---------------------------------------------------------------------------
// prep_gi: gi_T[t][col(768)][b] = x(t,b) @ W_ih^T + b_ih  (transposed output).
// ---------------------------------------------------------------------------
__global__ void prep_gi(const float* __restrict__ s0, const float* __restrict__ doc,
                        const int* __restrict__ tgt, const float* __restrict__ W_ih,
                        const float* __restrict__ b_ih, float* __restrict__ gi_T) {
    __shared__ float xs[8][256];
    const int r0 = blockIdx.x * 8;
    const int tid = threadIdx.x;
    for (int i = tid; i < 512; i += 256) {
        int row = i >> 6, c4 = i & 63;
        int r = r0 + row;              // r = t*128 + b
        int t = r >> 7, b = r & 127;
        const float* src;
        if (t == 0) src = s0 + (size_t)b * H_;
        else {
            int idx = tgt[b * T_ + t - 1];
            if (idx < 0) idx = 0;
            src = doc + ((size_t)b * S_ + idx) * H_;
        }
        *((float4*)&xs[row][c4 * 4]) = ((const float4*)src)[c4];
    }
    __syncthreads();
    const int j = tid;
    float acc[8][3];
#pragma unroll
    for (int r = 0; r < 8; ++r) { acc[r][0] = 0.f; acc[r][1] = 0.f; acc[r][2] = 0.f; }
    const float4* w0p = (const float4*)(W_ih + (size_t)j * H_);
    const float4* w1p = (const float4*)(W_ih + (size_t)(j + 256) * H_);
    const float4* w2p = (const float4*)(W_ih + (size_t)(j + 512) * H_);
    for (int c4 = 0; c4 < 64; ++c4) {
        float4 w0 = w0p[c4], w1 = w1p[c4], w2 = w2p[c4];
#pragma unroll
        for (int r = 0; r < 8; ++r) {
            float4 x4 = *((const float4*)&xs[r][c4 * 4]);
            acc[r][0] = fmaf(w0.x, x4.x, acc[r][0]); acc[r][0] = fmaf(w0.y, x4.y, acc[r][0]);
            acc[r][0] = fmaf(w0.z, x4.z, acc[r][0]); acc[r][0] = fmaf(w0.w, x4.w, acc[r][0]);
            acc[r][1] = fmaf(w1.x, x4.x, acc[r][1]); acc[r][1] = fmaf(w1.y, x4.y, acc[r][1]);
            acc[r][1] = fmaf(w1.z, x4.z, acc[r][1]); acc[r][1] = fmaf(w1.w, x4.w, acc[r][1]);
            acc[r][2] = fmaf(w2.x, x4.x, acc[r][2]); acc[r][2] = fmaf(w2.y, x4.y, acc[r][2]);
            acc[r][2] = fmaf(w2.z, x4.z, acc[r][2]); acc[r][2] = fmaf(w2.w, x4.w, acc[r][2]);
        }
    }
#pragma unroll
    for (int r = 0; r < 8; ++r) {
        int row = r0 + r;                 // t*128 + b
        int t = row >> 7, b = row & 127;
#pragma unroll
        for (int g = 0; g < 3; ++g)
            gi_T[((size_t)t * 768 + g * 256 + j) * B_ + b] = acc[r][g] + b_ih[g * 256 + j];
    }
}

// ---------------------------------------------------------------------------
// gru_all: 8 blocks x 1024 threads (block = 16 batches, 16 waves).
// Wave w owns cols [w*16, w*16+16) of each plane {r,z,n,q}: 4 N-tiles,
// 32 MFMA/step, all 32 weight fragments loaded up-front (max MLP).
// q(h(t-1)) computed in the same GEMM -> targets[t-1]; final q after loop.
// ---------------------------------------------------------------------------
__global__ __launch_bounds__(1024, 4) void gru_all(
        const float* __restrict__ h0, const ushort_t* __restrict__ Whh_bf,
        const ushort_t* __restrict__ Wq_bf, const float* __restrict__ b_hh,
        const float* __restrict__ bq, const float* __restrict__ gi_T,
        float* __restrict__ targets) {
    __shared__ char hbf[16 * 512];        // h [16][256] bf16, byte ^= ((b&7)<<4)
    const int tid = threadIdx.x;
    const int wv = tid >> 6, lane = tid & 63;
    const int r16 = lane & 15, g = lane >> 4;
    const int b0 = blockIdx.x * 16;

    if (tid < 512) {   // init h0 -> LDS bf16
        int b = tid >> 5, k8 = (tid & 31) * 8;
        const float* src = h0 + (size_t)(b0 + b) * H_ + k8;
        float4 v0 = *((const float4*)src);
        float4 v1 = *((const float4*)(src + 4));
        short8 p = pack_bf8(v0, v1);
        int byte = (b * 512 + k8 * 2) ^ ((b & 7) << 4);
        *((short8*)&hbf[byte]) = p;
    }

    const int c0 = wv * 16 + r16;          // owned column (0..255)
    const float bhr0 = b_hh[c0], bhz0 = b_hh[256 + c0], bhn0 = b_hh[512 + c0];
    const float bq0 = bq[c0];

    const ushort_t* wb[4];
    wb[0] = Whh_bf + (size_t)c0 * H_ + g * 8;                 // r
    wb[1] = Whh_bf + (size_t)(256 + c0) * H_ + g * 8;         // z
    wb[2] = Whh_bf + (size_t)(512 + c0) * H_ + g * 8;         // n
    wb[3] = Wq_bf  + (size_t)c0 * H_ + g * 8;                 // q

    __syncthreads();

    short8 af[8];
#pragma unroll
    for (int ks = 0; ks < 8; ++ks) {
        int byte = (r16 * 512 + ks * 64 + g * 16) ^ ((r16 & 7) << 4);
        af[ks] = *((const short8*)&hbf[byte]);
    }

#pragma unroll 1
    for (int t = 0; t < T_; ++t) {
        // gi loads issued early
        const float* gt = gi_T + (size_t)t * 768 * B_ + b0 + g * 4;
        f32x4 gir = *((const f32x4*)(gt + (size_t)c0 * B_));
        f32x4 giz = *((const f32x4*)(gt + (size_t)(256 + c0) * B_));
        f32x4 gin = *((const f32x4*)(gt + (size_t)(512 + c0) * B_));

        // all 32 weight fragments up-front: maximum memory-level parallelism
        short8 wf[4][8];
#pragma unroll
        for (int i = 0; i < 4; ++i)
#pragma unroll
            for (int ks = 0; ks < 8; ++ks)
                wf[i][ks] = *((const short8*)(wb[i] + ks * 32));

        f32x4 acc[4];
#pragma unroll
        for (int i = 0; i < 4; ++i) acc[i] = (f32x4){0.f, 0.f, 0.f, 0.f};
#pragma unroll
        for (int ks = 0; ks < 8; ++ks)
#pragma unroll
            for (int i = 0; i < 4; ++i)
                acc[i] = __builtin_amdgcn_mfma_f32_16x16x32_bf16(af[ks], wf[i][ks], acc[i], 0, 0, 0);

        // q(h(t-1)) -> targets[t-1]
        if (t >= 1) {
#pragma unroll
            for (int rr = 0; rr < 4; ++rr) {
                int bb = b0 + g * 4 + rr;
                targets[((size_t)(t - 1) * B_ + bb) * H_ + c0] = acc[3][rr] + bq0;
            }
        }

        // pointwise gates + h update (lane owns b = g*4+rr, col c0)
        float hnew[4];
#pragma unroll
        for (int rr = 0; rr < 4; ++rr) {
            int bb = g * 4 + rr;
            int byA = (bb * 512 + c0 * 2) ^ ((bb & 7) << 4);
            float ho = bf2f(*((const ushort_t*)&hbf[byA]));
            float rv = sigf(gir[rr] + acc[0][rr] + bhr0);
            float zv = sigf(giz[rr] + acc[1][rr] + bhz0);
            float nv = tanh_acc(fmaf(rv, acc[2][rr] + bhn0, gin[rr]));
            hnew[rr] = nv + zv * (ho - nv);
        }
        __syncthreads();   // all reads of h(t-1) complete
#pragma unroll
        for (int rr = 0; rr < 4; ++rr) {
            int bb = g * 4 + rr;
            int byA = (bb * 512 + c0 * 2) ^ ((bb & 7) << 4);
            *((ushort_t*)&hbf[byA]) = f2bf(hnew[rr]);
        }
        __syncthreads();   // h(t) visible
#pragma unroll
        for (int ks = 0; ks < 8; ++ks) {
            int byte = (r16 * 512 + ks * 64 + g * 16) ^ ((r16 & 7) << 4);
            af[ks] = *((const short8*)&hbf[byte]);
        }
    }

    // final q GEMM on h(9) -> targets[9]
    f32x4 q0 = (f32x4){0.f, 0.f, 0.f, 0.f};
    short8 wq[8];
#pragma unroll
    for (int ks = 0; ks < 8; ++ks) wq[ks] = *((const short8*)(wb[3] + ks * 32));
#pragma unroll
    for (int ks = 0; ks < 8; ++ks)
        q0 = __builtin_amdgcn_mfma_f32_16x16x32_bf16(af[ks], wq[ks], q0, 0, 0, 0);
#pragma unroll
    for (int rr = 0; rr < 4; ++rr) {
        int bb = b0 + g * 4 + rr;
        targets[((size_t)(T_ - 1) * B_ + bb) * H_ + c0] = q0[rr] + bq0;
    }
}

// ---------------------------------------------------------------------------
// energy: 256 blocks (= 1/CU, no tail) x 1024 threads (16 waves).
// Block = (b, half of S = 512 rows). Wd staged ONCE into XOR-swizzled LDS
// (128 KB): per-nt A-fragment loads become ~free LDS reads instead of
// global re-streams. Wave w: tile st = sh*4 + (w>>2), 32 s-rows (2 subtiles
// of 16). D layout: col(lane&15)=s, row(g*4+rr)=k.
// ---------------------------------------------------------------------------
__global__ __launch_bounds__(1024) void energy_kernel(
        const float* __restrict__ doc, const ushort_t* __restrict__ Wd_bf,
        const float* __restrict__ targets, const float* __restrict__ bd,
        const float* __restrict__ Ws, const float* __restrict__ bs,
        const int* __restrict__ slenp, float* __restrict__ out) {
    __shared__ ushort_t wd_l[65536];      // [256][256] bf16, byte^=((row&7)<<4)
    __shared__ float tg[T_][256];
    __shared__ float ws_l[256], bd_l[256];
    const int bid = blockIdx.x;
    const int b = bid >> 1, sh = bid & 1;
    const int tid = threadIdx.x;

    const int w = tid >> 6, lane = tid & 63;
    const int r16 = lane & 15, g = lane >> 4;
    const int st = sh * 4 + (w >> 2);
    const int s0_loc = st * 128 + (w & 3) * 32 + r16;    // subtile 2 at +16

    // issue doc loads first (independent of LDS staging)
    const float* drow0 = doc + ((size_t)b * S_ + s0_loc) * H_ + g * 8;
    const float* drow1 = drow0 + (size_t)16 * H_;
    short8 bdoc0[8], bdoc1[8];
#pragma unroll
    for (int ks = 0; ks < 8; ++ks) {
        float4 v0 = *((const float4*)(drow0 + ks * 32));
        float4 v1 = *((const float4*)(drow0 + ks * 32 + 4));
        bdoc0[ks] = pack_bf8(v0, v1);
        float4 u0 = *((const float4*)(drow1 + ks * 32));
        float4 u1 = *((const float4*)(drow1 + ks * 32 + 4));
        bdoc1[ks] = pack_bf8(u0, u1);
    }

    // stage Wd -> swizzled LDS: 8 passes x 16 KB, global-coalesced
#pragma unroll
    for (int p = 0; p < 8; ++p) {
        int idx = p * 1024 + tid;          // short8 index, 8192 total
        int row = idx >> 5;                // 32 x short8 per 256-col row
        int cb = (idx & 31) * 16;          // column byte offset
        short8 v = *((const short8*)(Wd_bf + (size_t)idx * 8));
        int byte = row * 512 + (cb ^ ((row & 7) << 4));
        *((short8*)((char*)wd_l + byte)) = v;
    }
    // tg / ws / bd staging
    if (tid < 640) {
        int t = tid >> 6, k4 = tid & 63;
        ((float4*)&tg[t][0])[k4] = *((const float4*)&targets[((size_t)t * B_ + b) * H_ + k4 * 4]);
    } else if (tid < 704) {
        ((float4*)ws_l)[tid - 640] = ((const float4*)Ws)[tid - 640];
    } else if (tid < 768) {
        ((float4*)bd_l)[tid - 704] = ((const float4*)bd)[tid - 704];
    }
    __syncthreads();

    f32x2 e2[T_];
#pragma unroll
    for (int t = 0; t < T_; ++t) e2[t] = sp2(0.f);

    const int kq = g * 4;
    const int xmask = (r16 & 7) << 4;

#pragma unroll 1
    for (int nt = 0; nt < 16; ++nt) {
        const int k0 = nt * 16 + kq;
        const int rowb = (nt * 16 + r16) * 512;
        short8 awd[8];
#pragma unroll
        for (int ks = 0; ks < 8; ++ks) {
            int byte = rowb + ((ks * 64 + g * 16) ^ xmask);
            awd[ks] = *((const short8*)((const char*)wd_l + byte));
        }
        f32x4 bd4 = *((const f32x4*)&bd_l[k0]);
        f32x4 a00 = bd4;
        f32x4 a01 = {0.f, 0.f, 0.f, 0.f};
        f32x4 a10 = bd4;
        f32x4 a11 = {0.f, 0.f, 0.f, 0.f};
#pragma unroll
        for (int ks = 0; ks < 4; ++ks) {
            a00 = __builtin_amdgcn_mfma_f32_16x16x32_bf16(awd[ks],     bdoc0[ks],     a00, 0, 0, 0);
            a01 = __builtin_amdgcn_mfma_f32_16x16x32_bf16(awd[ks + 4], bdoc0[ks + 4], a01, 0, 0, 0);
            a10 = __builtin_amdgcn_mfma_f32_16x16x32_bf16(awd[ks],     bdoc1[ks],     a10, 0, 0, 0);
            a11 = __builtin_amdgcn_mfma_f32_16x16x32_bf16(awd[ks + 4], bdoc1[ks + 4], a11, 0, 0, 0);
        }
        f32x4 pA = a00 + a01;
        f32x4 pB = a10 + a11;
        f32x4 ws4 = *((const f32x4*)&ws_l[k0]);

        f32x4 tgc = *((const f32x4*)&tg[0][k0]);
#pragma unroll
        for (int t = 0; t < T_; ++t) {
            f32x4 tgn;
            if (t + 1 < T_) tgn = *((const f32x4*)&tg[t + 1][k0]);
#pragma unroll
            for (int rr = 0; rr < 4; ++rr) {
                f32x2 x = (f32x2){pA[rr], pB[rr]} + sp2(tgc[rr]);
                f32x2 th = tanh2(x);
                e2[t] += th * sp2(ws4[rr]);
            }
            if (t + 1 < T_) tgc = tgn;
        }
    }

    // reduce over g (lane bits 4,5)
    float e0[T_], e1[T_];
#pragma unroll
    for (int t = 0; t < T_; ++t) {
        e0[t] = e2[t][0];
        e1[t] = e2[t][1];
        e0[t] += __shfl_xor(e0[t], 16);
        e0[t] += __shfl_xor(e0[t], 32);
        e1[t] += __shfl_xor(e1[t], 16);
        e1[t] += __shfl_xor(e1[t], 32);
    }

    const int slen = slenp[b];
    const float bs0 = bs[0];
    const bool pad0 = (s0_loc >= slen);
    const bool pad1 = (s0_loc + 16 >= slen);
    float* obase = out + (size_t)b * S_ + s0_loc;
#pragma unroll
    for (int tt = g; tt < T_; tt += 4) {
        obase[(size_t)tt * B_ * S_]      = pad0 ? NEG_INF_ : (e0[tt] + bs0);
        obase[(size_t)tt * B_ * S_ + 16] = pad1 ? NEG_INF_ : (e1[tt] + bs0);
    }
}

// ---------------------------------------------------------------------------
extern "C" void kernel_launch(void* const* d_in, const int* in_sizes, int n_in,
                              void* d_out, int out_size, void* d_ws, size_t ws_size,
                              hipStream_t stream) {
    (void)in_sizes; (void)n_in; (void)out_size; (void)ws_size;
    const float* s0   = (const float*)d_in[0];
    const float* h0   = (const float*)d_in[1];
    const float* doc  = (const float*)d_in[2];
    const float* W_ih = (const float*)d_in[3];
    const float* W_hh = (const float*)d_in[4];
    const float* b_ih = (const float*)d_in[5];
    const float* b_hh = (const float*)d_in[6];
    const float* Wq   = (const float*)d_in[7];
    const float* bq   = (const float*)d_in[8];
    const float* Wd   = (const float*)d_in[9];
    const float* bd   = (const float*)d_in[10];
    const float* Ws   = (const float*)d_in[11];
    const float* bs   = (const float*)d_in[12];
    const int*   tgt  = (const int*)d_in[13];
    const int*   slen = (const int*)d_in[14];

    float* out_score = (float*)d_out;                       // [10][128][1024]
    float* out_mask  = out_score + T_ * B_ * S_;            // [128][1024]

    char* ws = (char*)d_ws;
    ushort_t* Whh_bf  = (ushort_t*)(ws + 0);                //  393216 B
    ushort_t* Wq_bf   = (ushort_t*)(ws + 393216);           //  131072 B
    ushort_t* Wd_bf   = (ushort_t*)(ws + 524288);           //  131072 B
    float*    gi_T    = (float*)(ws + 655360);              // 3932160 B
    float*    targets = (float*)(ws + 4587520);             // 1310720 B (end 5898240)

    prep_conv<<<1792, 256, 0, stream>>>(W_hh, Wq, Wd, slen, Whh_bf, Wq_bf, Wd_bf, out_mask);
    prep_gi<<<160, 256, 0, stream>>>(s0, doc, tgt, W_ih, b_ih, gi_T);
    gru_all<<<8, 1024, 0, stream>>>(h0, Whh_bf, Wq_bf, b_hh, bq, gi_T, targets);
    energy_kernel<<<256, 1024, 0, stream>>>(doc, Wd_bf, targets, bd, Ws, bs, slen, out_score);
}

// Round 8
// 179.007 us; speedup vs baseline: 1.6132x; 1.6132x over previous
//
#include <hip/hip_runtime.h>

typedef unsigned short ushort_t;
typedef unsigned int uint_t;
typedef __attribute__((ext_vector_type(8))) short short8;   // 8 x bf16 (4 VGPRs)
typedef __attribute__((ext_vector_type(4))) float f32x4;

#define B_   128
#define S_   1024
#define H_   256
#define T_   10
#define NEG_INF_ -1e8f

static __device__ __forceinline__ ushort_t f2bf(float x) {
    unsigned int u = __float_as_uint(x);
    unsigned int r = u + 0x7FFFu + ((u >> 16) & 1u);   // RNE
    return (ushort_t)(r >> 16);
}
static __device__ __forceinline__ float bflo(uint_t w) {
    return __uint_as_float(w << 16);
}
static __device__ __forceinline__ float bfhi(uint_t w) {
    return __uint_as_float(w & 0xFFFF0000u);
}
static __device__ __forceinline__ float sigf(float x) {
    return 1.0f / (1.0f + __expf(-x));
}
static __device__ __forceinline__ float tanh_acc(float x) {
    return 2.0f / (1.0f + __expf(-2.0f * x)) - 1.0f;
}
// clamped odd poly tanh: 5 VALU, |err|<~0.025 (threshold 2e6)
static __device__ __forceinline__ float tanh_fast(float x) {
    float u = x * x;
    float p = fmaf(0.019063f, u, -0.18852f);
    p = fmaf(p, u, 0.93106f);
    float r = x * p;
    return __builtin_amdgcn_fmed3f(r, -1.0f, 1.0f);
}
static __device__ __forceinline__ short8 pack_bf8(float4 a, float4 b) {
    short8 r;
    r[0] = (short)f2bf(a.x); r[1] = (short)f2bf(a.y);
    r[2] = (short)f2bf(a.z); r[3] = (short)f2bf(a.w);
    r[4] = (short)f2bf(b.x); r[5] = (short)f2bf(b.y);
    r[6] = (short)f2bf(b.z); r[7] = (short)f2bf(b.w);
    return r;
}

// ---------------------------------------------------------------------------
// prep_transpose: 7 weight planes (ih_r/z/n, hh_r/z/n, q) 256x256 fp32 ->
// transposed bf16-pair planes P2[c2][j]. 112 blocks.
// ---------------------------------------------------------------------------
__global__ void prep_transpose(const float* __restrict__ W_ih,
                               const float* __restrict__ W_hh,
                               const float* __restrict__ Wq,
                               uint_t* __restrict__ planes) {
    __shared__ float lds[64][65];
    const int p = blockIdx.x >> 4, tile = blockIdx.x & 15;
    const int j0 = (tile >> 2) * 64, c0 = (tile & 3) * 64;
    const float* src;
    if (p < 3)      src = W_ih + (size_t)p * 65536;
    else if (p < 6) src = W_hh + (size_t)(p - 3) * 65536;
    else            src = Wq;
    uint_t* dst = planes + (size_t)p * 32768;
    const int tid = threadIdx.x;
#pragma unroll
    for (int p4 = 0; p4 < 4; ++p4) {
        int i = p4 * 256 + tid;
        int jj = i >> 4, cc4 = (i & 15) * 4;
        float4 v = *((const float4*)&src[(size_t)(j0 + jj) * 256 + c0 + cc4]);
        lds[jj][cc4]     = v.x;
        lds[jj][cc4 + 1] = v.y;
        lds[jj][cc4 + 2] = v.z;
        lds[jj][cc4 + 3] = v.w;
    }
    __syncthreads();
#pragma unroll
    for (int p8 = 0; p8 < 8; ++p8) {
        int i = p8 * 256 + tid;
        int c2 = i >> 6, j = i & 63;
        float lo = lds[j][c2 * 2], hi = lds[j][c2 * 2 + 1];
        uint_t val = (uint_t)f2bf(lo) | ((uint_t)f2bf(hi) << 16);
        dst[(size_t)(c0 / 2 + c2) * 256 + j0 + j] = val;
    }
}

// ---------------------------------------------------------------------------
// prep_small: Wd -> bf16 row-major, mask output. grid = 768*256 exactly.
// ---------------------------------------------------------------------------
__global__ void prep_small(const float* __restrict__ Wd, const int* __restrict__ slen,
                           ushort_t* __restrict__ Wd_bf, float* __restrict__ out_mask) {
    int i = blockIdx.x * 256 + threadIdx.x;
    if (i < 65536) { Wd_bf[i] = f2bf(Wd[i]); return; }
    i -= 65536;
    int b = i >> 10, s = i & 1023;
    out_mask[i] = (s >= slen[b]) ? 1.0f : 0.0f;
}

// ---------------------------------------------------------------------------
// gru_all: 128 blocks x 512 threads. thread = (j, half); each half computes
// half the 256-wide dot products (split-K), partials combined via LDS.
// gi phase split by t across halves. Loads explicitly batched into register
// arrays (24 in flight) so L2 latency amortizes -- R3 version had VGPR=36
// and ~6 loads in flight -> latency-starved at 146us.
// ---------------------------------------------------------------------------
__global__ __launch_bounds__(512) void gru_all(
        const float* __restrict__ s0, const float* __restrict__ h0,
        const float* __restrict__ doc, const int* __restrict__ tgt,
        const uint_t* __restrict__ planes, const float* __restrict__ b_ih,
        const float* __restrict__ b_hh, const float* __restrict__ bq,
        float* __restrict__ targets) {
    __shared__ float xs[T_][256];
    __shared__ float hs[256];
    __shared__ float pr[256], pz[256], pn[256], pq[256];
    const int b = blockIdx.x;
    const int tid = threadIdx.x;
    const int j = tid & 255, half = tid >> 8;

    const uint_t* ihr = planes;
    const uint_t* ihz = planes + 32768;
    const uint_t* ihn = planes + 2 * 32768;
    const uint_t* hhr = planes + 3 * 32768;
    const uint_t* hhz = planes + 4 * 32768;
    const uint_t* hhn = planes + 5 * 32768;
    const uint_t* qT  = planes + 6 * 32768;

    // gather x(t): t=0 -> s0[b], t>=1 -> doc[b, tgt[b][t-1]]
    for (int i = tid; i < 640; i += 512) {
        int t = i >> 6, c4 = i & 63;
        const float* src;
        if (t == 0) src = s0 + (size_t)b * H_;
        else {
            int idx = tgt[b * T_ + t - 1];
            if (idx < 0) idx = 0;
            src = doc + ((size_t)b * S_ + idx) * H_;
        }
        ((float4*)&xs[t][0])[c4] = ((const float4*)src)[c4];
    }
    if (half == 0) hs[j] = h0[(size_t)b * H_ + j];
    const float bhr = b_hh[j], bhz = b_hh[j + 256], bhn = b_hh[j + 512];
    const float bqj = bq[j];
    const float bihr = b_ih[j], bihz = b_ih[j + 256], bihn = b_ih[j + 512];
    __syncthreads();

    // gi phase: this half owns t in [half*5, half*5+5); batched loads
    float g_r[5], g_z[5], g_n[5];
#pragma unroll
    for (int u = 0; u < 5; ++u) { g_r[u] = bihr; g_z[u] = bihz; g_n[u] = bihn; }
    const int tbase = half * 5;
#pragma unroll 1
    for (int bb = 0; bb < 16; ++bb) {
        uint_t wr8[8], wz8[8], wn8[8];
#pragma unroll
        for (int v = 0; v < 8; ++v) {
            int c2 = bb * 8 + v;
            wr8[v] = ihr[c2 * 256 + j];
            wz8[v] = ihz[c2 * 256 + j];
            wn8[v] = ihn[c2 * 256 + j];
        }
#pragma unroll
        for (int v = 0; v < 8; ++v) {
            int c2 = bb * 8 + v;
            float wr0 = bflo(wr8[v]), wr1 = bfhi(wr8[v]);
            float wz0 = bflo(wz8[v]), wz1 = bfhi(wz8[v]);
            float wn0 = bflo(wn8[v]), wn1 = bfhi(wn8[v]);
#pragma unroll
            for (int u = 0; u < 5; ++u) {
                float2 x2 = *((const float2*)&xs[tbase + u][c2 * 2]);
                g_r[u] = fmaf(wr0, x2.x, g_r[u]); g_r[u] = fmaf(wr1, x2.y, g_r[u]);
                g_z[u] = fmaf(wz0, x2.x, g_z[u]); g_z[u] = fmaf(wz1, x2.y, g_z[u]);
                g_n[u] = fmaf(wn0, x2.x, g_n[u]); g_n[u] = fmaf(wn1, x2.y, g_n[u]);
            }
        }
    }

    const int c2base = half * 64;
    const uint_t* hhr_h = hhr + (size_t)c2base * 256 + j;
    const uint_t* hhz_h = hhz + (size_t)c2base * 256 + j;
    const uint_t* hhn_h = hhn + (size_t)c2base * 256 + j;
    const uint_t* qT_h  = qT  + (size_t)c2base * 256 + j;

    // recurrent chain, unrolled over t so gi indices stay static
#pragma unroll
    for (int t = 0; t < T_; ++t) {
        const bool holder = (half == (t >= 5 ? 1 : 0));
        const int u = (t < 5) ? t : t - 5;
        float ar = 0.f, az = 0.f, an = 0.f;
#pragma unroll 1
        for (int bb = 0; bb < 8; ++bb) {       // 8 batches x 8 c2i, 24 loads in flight
            uint_t wr8[8], wz8[8], wn8[8];
#pragma unroll
            for (int v = 0; v < 8; ++v) {
                int c2i = bb * 8 + v;
                wr8[v] = hhr_h[c2i * 256];
                wz8[v] = hhz_h[c2i * 256];
                wn8[v] = hhn_h[c2i * 256];
            }
#pragma unroll
            for (int v = 0; v < 8; ++v) {
                int c2i = bb * 8 + v;
                float2 h2 = *((const float2*)&hs[(c2base + c2i) * 2]);
                ar = fmaf(bflo(wr8[v]), h2.x, ar); ar = fmaf(bfhi(wr8[v]), h2.y, ar);
                az = fmaf(bflo(wz8[v]), h2.x, az); az = fmaf(bfhi(wz8[v]), h2.y, az);
                an = fmaf(bflo(wn8[v]), h2.x, an); an = fmaf(bfhi(wn8[v]), h2.y, an);
            }
        }
        if (!holder) { pr[j] = ar; pz[j] = az; pn[j] = an; }
        __syncthreads();
        if (holder) {
            float art = ar + pr[j] + bhr;
            float azt = az + pz[j] + bhz;
            float ant = an + pn[j] + bhn;
            float r = sigf(g_r[u] + art);
            float z = sigf(g_z[u] + azt);
            float n = tanh_acc(fmaf(r, ant, g_n[u]));
            float hold = hs[j];
            hs[j] = fmaf(z, hold - n, n);      // (1-z)n + z h
        }
        __syncthreads();
        float q = 0.f;
#pragma unroll 1
        for (int bb = 0; bb < 4; ++bb) {       // 4 batches x 16, 16 loads in flight
            uint_t wq16[16];
#pragma unroll
            for (int v = 0; v < 16; ++v)
                wq16[v] = qT_h[(bb * 16 + v) * 256];
#pragma unroll
            for (int v = 0; v < 16; ++v) {
                int c2i = bb * 16 + v;
                float2 h2 = *((const float2*)&hs[(c2base + c2i) * 2]);
                q = fmaf(bflo(wq16[v]), h2.x, q); q = fmaf(bfhi(wq16[v]), h2.y, q);
            }
        }
        if (!holder) pq[j] = q;
        __syncthreads();
        if (holder) targets[((size_t)t * B_ + b) * H_ + j] = q + pq[j] + bqj;
    }
}

// ---------------------------------------------------------------------------
// energy: block (b, s-tile of 128 = TWO 64-row MFMA tiles). Wd fragments and
// tg/ws LDS reads shared by both tiles. D layout: col(lane&15)=s, row=k.
// (exact R3-proposal version -- part of the 233us known-good config)
// ---------------------------------------------------------------------------
__global__ __launch_bounds__(256, 3) void energy_kernel(
        const float* __restrict__ doc, const ushort_t* __restrict__ Wd_bf,
        const float* __restrict__ targets, const float* __restrict__ bd,
        const float* __restrict__ Ws, const float* __restrict__ bs,
        const int* __restrict__ slenp, float* __restrict__ out) {
    __shared__ float tg[T_][256];
    __shared__ float ws_l[256], bd_l[256];
    const int bid = blockIdx.x;
    const int b = bid >> 3, st = bid & 7;
    const int tid = threadIdx.x;

    for (int i = tid; i < 640; i += 256) {
        int t = i >> 6, k4 = i & 63;
        ((float4*)&tg[t][0])[k4] = *((const float4*)&targets[((size_t)t * B_ + b) * H_ + k4 * 4]);
    }
    if (tid < 64) ((float4*)ws_l)[tid] = ((const float4*)Ws)[tid];
    else if (tid < 128) ((float4*)bd_l)[tid - 64] = ((const float4*)bd)[tid - 64];

    const int lane = tid & 63, w = tid >> 6;
    const int r16 = lane & 15, g = lane >> 4;

    const int s0_loc = st * 128 + w * 16 + r16;
    const float* drow0 = doc + ((size_t)b * S_ + s0_loc) * H_ + g * 8;
    const float* drow1 = drow0 + (size_t)64 * H_;
    short8 bdoc0[8], bdoc1[8];
#pragma unroll
    for (int ks = 0; ks < 8; ++ks) {
        float4 v0 = *((const float4*)(drow0 + ks * 32));
        float4 v1 = *((const float4*)(drow0 + ks * 32 + 4));
        bdoc0[ks] = pack_bf8(v0, v1);
        float4 u0 = *((const float4*)(drow1 + ks * 32));
        float4 u1 = *((const float4*)(drow1 + ks * 32 + 4));
        bdoc1[ks] = pack_bf8(u0, u1);
    }
    __syncthreads();

    float e0[T_], e1[T_];
#pragma unroll
    for (int t = 0; t < T_; ++t) { e0[t] = 0.f; e1[t] = 0.f; }

    const ushort_t* wbase = Wd_bf + (size_t)r16 * H_ + g * 8;
    const int kq = g * 4;

#pragma unroll 2
    for (int nt = 0; nt < 16; ++nt) {
        const int k0 = nt * 16 + kq;
        const ushort_t* wrow = wbase + (size_t)(nt * 16) * H_;
        short8 awd[8];
#pragma unroll
        for (int ks = 0; ks < 8; ++ks) awd[ks] = *((const short8*)(wrow + ks * 32));
        f32x4 bd4 = *((const f32x4*)&bd_l[k0]);
        f32x4 a00 = bd4;
        f32x4 a01 = {0.f, 0.f, 0.f, 0.f};
        f32x4 a10 = bd4;
        f32x4 a11 = {0.f, 0.f, 0.f, 0.f};
#pragma unroll
        for (int ks = 0; ks < 4; ++ks) {
            a00 = __builtin_amdgcn_mfma_f32_16x16x32_bf16(awd[ks],     bdoc0[ks],     a00, 0, 0, 0);
            a01 = __builtin_amdgcn_mfma_f32_16x16x32_bf16(awd[ks + 4], bdoc0[ks + 4], a01, 0, 0, 0);
            a10 = __builtin_amdgcn_mfma_f32_16x16x32_bf16(awd[ks],     bdoc1[ks],     a10, 0, 0, 0);
            a11 = __builtin_amdgcn_mfma_f32_16x16x32_bf16(awd[ks + 4], bdoc1[ks + 4], a11, 0, 0, 0);
        }
        f32x4 pA = a00 + a01;
        f32x4 pB = a10 + a11;
        f32x4 ws4 = *((const f32x4*)&ws_l[k0]);
#pragma unroll
        for (int t = 0; t < T_; ++t) {
            f32x4 tg4 = *((const f32x4*)&tg[t][k0]);
#pragma unroll
            for (int rr = 0; rr < 4; ++rr) {
                e0[t] = fmaf(tanh_fast(pA[rr] + tg4[rr]), ws4[rr], e0[t]);
                e1[t] = fmaf(tanh_fast(pB[rr] + tg4[rr]), ws4[rr], e1[t]);
            }
        }
    }

    // reduce over g (lane bits 4,5)
#pragma unroll
    for (int t = 0; t < T_; ++t) {
        e0[t] += __shfl_xor(e0[t], 16);
        e0[t] += __shfl_xor(e0[t], 32);
        e1[t] += __shfl_xor(e1[t], 16);
        e1[t] += __shfl_xor(e1[t], 32);
    }

    const int slen = slenp[b];
    const float bs0 = bs[0];
    const bool pad0 = (s0_loc >= slen);
    const bool pad1 = (s0_loc + 64 >= slen);
    float* obase = out + (size_t)b * S_ + s0_loc;
#pragma unroll
    for (int tt = g; tt < T_; tt += 4) {
        obase[(size_t)tt * B_ * S_]      = pad0 ? NEG_INF_ : (e0[tt] + bs0);
        obase[(size_t)tt * B_ * S_ + 64] = pad1 ? NEG_INF_ : (e1[tt] + bs0);
    }
}

// ---------------------------------------------------------------------------
extern "C" void kernel_launch(void* const* d_in, const int* in_sizes, int n_in,
                              void* d_out, int out_size, void* d_ws, size_t ws_size,
                              hipStream_t stream) {
    (void)in_sizes; (void)n_in; (void)out_size; (void)ws_size;
    const float* s0   = (const float*)d_in[0];
    const float* h0   = (const float*)d_in[1];
    const float* doc  = (const float*)d_in[2];
    const float* W_ih = (const float*)d_in[3];
    const float* W_hh = (const float*)d_in[4];
    const float* b_ih = (const float*)d_in[5];
    const float* b_hh = (const float*)d_in[6];
    const float* Wq   = (const float*)d_in[7];
    const float* bq   = (const float*)d_in[8];
    const float* Wd   = (const float*)d_in[9];
    const float* bd   = (const float*)d_in[10];
    const float* Ws   = (const float*)d_in[11];
    const float* bs   = (const float*)d_in[12];
    const int*   tgt  = (const int*)d_in[13];
    const int*   slen = (const int*)d_in[14];

    float* out_score = (float*)d_out;                       // [10][128][1024]
    float* out_mask  = out_score + T_ * B_ * S_;            // [128][1024]

    char* ws = (char*)d_ws;
    uint_t*   planes  = (uint_t*)(ws + 0);                  // 917504 B
    ushort_t* Wd_bf   = (ushort_t*)(ws + 917504);           // 131072 B
    float*    targets = (float*)(ws + 1048576);             // 1310720 B

    prep_transpose<<<112, 256, 0, stream>>>(W_ih, W_hh, Wq, planes);
    prep_small<<<768, 256, 0, stream>>>(Wd, slen, Wd_bf, out_mask);
    gru_all<<<128, 512, 0, stream>>>(s0, h0, doc, tgt, planes, b_ih, b_hh, bq, targets);
    energy_kernel<<<1024, 256, 0, stream>>>(doc, Wd_bf, targets, bd, Ws, bs, slen, out_score);
}